// Round 19
// baseline (229.372 us; speedup 1.0000x reference)
//
#include <hip/hip_runtime.h>
#include <hip/hip_bf16.h>

#define NROW 131072   // B*L
#define D 256
#define K 320
#define BN_EPS 1e-5f
#define FIXSCALE 16777216.0f   // 2^24 fixed-point for deterministic atomics

typedef _Float16 half8 __attribute__((ext_vector_type(8)));
typedef float f32x4 __attribute__((ext_vector_type(4)));

// ws layout:
//   u64 acc[512]   @ 0      (4 KB)
//   f32 meanb[256] @ 4096
//   f32 rsb[256]   @ 5120
//   f32 cnorm[320] @ 6144
//   f16 cbx        @ 8192   (320 KB) codebook fragments:
//     tile nt(0..19) = 16 codes; tile base = nt*16384 B; hi half = first 8 KB
//     (ks*1024 B + lane*16), lo half = second 8 KB. MFMA B-fragment: lane l
//     holds code = nt*16 + (l&15), k = ks*32 + (l>>4)*8 .. +8

// ---------------- kernel 1: per-block channel partials -> fixed-point atomics
// float4 loads; ascending-row accumulation -> bit-identical partials (R17/18).
__global__ __launch_bounds__(256) void k_stats_partial(const float* __restrict__ x,
                                                       unsigned long long* __restrict__ acc) {
  const int q = threadIdx.x & 63;     // channel quad 0..63
  const int g2 = threadIdx.x >> 6;    // slab within block
  const int slab = (int)blockIdx.x * 4 + g2;   // 0..511
  const float* p = x + (size_t)slab * 256 * D + q * 4;
  float s0 = 0.f, s1 = 0.f, s2 = 0.f, s3 = 0.f;
  float q0 = 0.f, q1 = 0.f, q2 = 0.f, q3 = 0.f;
  #pragma unroll 4
  for (int r = 0; r < 256; ++r) {
    float4 v = *(const float4*)(p + (size_t)r * D);
    s0 += v.x; q0 = fmaf(v.x, v.x, q0);
    s1 += v.y; q1 = fmaf(v.y, v.y, q1);
    s2 += v.z; q2 = fmaf(v.z, v.z, q2);
    s3 += v.w; q3 = fmaf(v.w, v.w, q3);
  }
  atomicAdd(&acc[q * 4 + 0],       (unsigned long long)(long long)llrintf(s0 * FIXSCALE));
  atomicAdd(&acc[q * 4 + 1],       (unsigned long long)(long long)llrintf(s1 * FIXSCALE));
  atomicAdd(&acc[q * 4 + 2],       (unsigned long long)(long long)llrintf(s2 * FIXSCALE));
  atomicAdd(&acc[q * 4 + 3],       (unsigned long long)(long long)llrintf(s3 * FIXSCALE));
  atomicAdd(&acc[256 + q * 4 + 0], (unsigned long long)(long long)llrintf(q0 * FIXSCALE));
  atomicAdd(&acc[256 + q * 4 + 1], (unsigned long long)(long long)llrintf(q1 * FIXSCALE));
  atomicAdd(&acc[256 + q * 4 + 2], (unsigned long long)(long long)llrintf(q2 * FIXSCALE));
  atomicAdd(&acc[256 + q * 4 + 3], (unsigned long long)(long long)llrintf(q3 * FIXSCALE));
}

// ---------------- kernel 2: finalize stats + codebook norms -----------------
__global__ __launch_bounds__(256) void k_stats_final(const unsigned long long* __restrict__ acc,
                                                     const float* __restrict__ cb,
                                                     float* __restrict__ meanb,
                                                     float* __restrict__ rsb,
                                                     float* __restrict__ cnorm) {
  const int t = threadIdx.x;
  if (blockIdx.x == 0) {
    double s = (double)(long long)acc[t]       / (double)FIXSCALE;
    double q = (double)(long long)acc[256 + t] / (double)FIXSCALE;
    double mean = s / (double)NROW;
    double var  = q / (double)NROW - mean * mean;
    meanb[t] = (float)mean;
    rsb[t]   = (float)(1.0 / sqrt(var + (double)BN_EPS));
  } else {
    for (int code = t; code < K; code += 256) {
      const float* c = cb + (size_t)code * D;
      float s = 0.f;
      for (int dd = 0; dd < D; ++dd) s = fmaf(c[dd], c[dd], s);
      cnorm[code] = s;
    }
  }
}

// ---------------- kernel 2b: split codebook to fp16 hi/lo fragments ---------
// blocks 0..159: prep (nt = b>>3, ks = b&7); block 160: zero stat accumulators
__global__ __launch_bounds__(64) void k_cbprep(const float* __restrict__ cb,
                                               _Float16* __restrict__ cbx,
                                               unsigned long long* __restrict__ acc) {
  const int b = blockIdx.x;
  const int l = threadIdx.x;
  if (b == 160) {
    #pragma unroll
    for (int j = 0; j < 8; ++j) acc[j * 64 + l] = 0ull;
    return;
  }
  const int nt = b >> 3;
  const int ks = b & 7;
  const int code = nt * 16 + (l & 15);
  const int d0 = ks * 32 + (l >> 4) * 8;
  const float* src = cb + (size_t)code * D + d0;
  const size_t bh = ((size_t)(nt * 2 + 0) * 8 + ks) * 512 + l * 8;
  const size_t bl = ((size_t)(nt * 2 + 1) * 8 + ks) * 512 + l * 8;
  #pragma unroll
  for (int j = 0; j < 8; ++j) {
    float v = src[j];
    _Float16 h = (_Float16)v;
    _Float16 lo = (_Float16)(v - (float)h);
    cbx[bh + j] = h;
    cbx[bl + j] = lo;
  }
}

// ---------------- kernel 3: R14 + split-B (bh via LDS, bl via L2) -----------
// 2048 blocks x 256 thr (4 waves x 16 rows). Wave wv owns rows row0+wv*16..+16
// vs ALL 320 codes. Only the HI half-chunks (8 KB) are LDS-staged -> LDS
// read+write traffic halves vs R14. bl fragments are loaded per-wave straight
// from L2-resident cbx (1 KB x 8 per chunk), issued at iteration top and
// hidden by TLP. Operand values and per-acc MFMA order are BIT-IDENTICAL to
// R14 -> indices unchanged.
__global__ __launch_bounds__(256) void k_main(const float* __restrict__ x,
                                              const float* __restrict__ w,
                                              const float* __restrict__ bias,
                                              const float* __restrict__ cb,
                                              const float* __restrict__ meanb,
                                              const float* __restrict__ rsb,
                                              const float* __restrict__ cnorm,
                                              const _Float16* __restrict__ cbx,
                                              float* __restrict__ out) {
  __shared__ _Float16 Bbuf[2][4096];    // 2 x 8 KB hi-chunk slots
  __shared__ float sxs[64];             // per-row |xb|^2
  __shared__ int bsel[64];

  const int t = threadIdx.x;
  const int lane = t & 63;
  const int wv = t >> 6;              // wave 0..3
  const int c15 = lane & 15;
  const int g = lane >> 4;
  const int row0 = (int)blockIdx.x * 64;

  // ---- staging: hi-chunk c = 8 KB; 256 thr x 32 B = 2 x float4 per thread --
  float4 s0, s1;
#define ISSUE(c) {                                                      \
    const char* p_ = (const char*)cbx + (size_t)(c) * 16384 + (size_t)t * 16; \
    s0 = *(const float4*)(p_);                                          \
    s1 = *(const float4*)(p_ + 4096);                                   \
  }
#define WRITE(b) {                                                      \
    char* q_ = (char*)Bbuf[(b)] + t * 16;                               \
    *(float4*)(q_)        = s0;                                         \
    *(float4*)(q_ + 4096) = s1;                                         \
  }

  ISSUE(0);

  // ---- x -> A fragments in registers (normalize + fp16 hi/lo split) ----
  // lane l: row = row0 + wv*16 + (l&15), k-elems (l>>4)*8 + ks*32 .. +8
  half8 ah[8], al[8];
  float accq = 0.f;
  {
    const int arow = row0 + wv * 16 + c15;
    const int dbase = g * 8;
    const float* xp = x + (size_t)arow * D + dbase;
    #pragma unroll
    for (int ks = 0; ks < 8; ++ks) {
      const int d0 = dbase + ks * 32;
      float4 xa = *(const float4*)(xp + ks * 32);
      float4 xb2 = *(const float4*)(xp + ks * 32 + 4);
      float4 m0 = *(const float4*)(meanb + d0);
      float4 m1 = *(const float4*)(meanb + d0 + 4);
      float4 r0 = *(const float4*)(rsb + d0);
      float4 r1 = *(const float4*)(rsb + d0 + 4);
      float4 w0 = *(const float4*)(w + d0);
      float4 w1 = *(const float4*)(w + d0 + 4);
      float4 b0 = *(const float4*)(bias + d0);
      float4 b1 = *(const float4*)(bias + d0 + 4);
      float o0 = ((xa.x - m0.x) * r0.x) * w0.x + b0.x;
      float o1 = ((xa.y - m0.y) * r0.y) * w0.y + b0.y;
      float o2 = ((xa.z - m0.z) * r0.z) * w0.z + b0.z;
      float o3 = ((xa.w - m0.w) * r0.w) * w0.w + b0.w;
      float o4 = ((xb2.x - m1.x) * r1.x) * w1.x + b1.x;
      float o5 = ((xb2.y - m1.y) * r1.y) * w1.y + b1.y;
      float o6 = ((xb2.z - m1.z) * r1.z) * w1.z + b1.z;
      float o7 = ((xb2.w - m1.w) * r1.w) * w1.w + b1.w;
      accq = fmaf(o0, o0, accq); accq = fmaf(o1, o1, accq);
      accq = fmaf(o2, o2, accq); accq = fmaf(o3, o3, accq);
      accq = fmaf(o4, o4, accq); accq = fmaf(o5, o5, accq);
      accq = fmaf(o6, o6, accq); accq = fmaf(o7, o7, accq);
      _Float16 h;
      h = (_Float16)o0; ah[ks][0] = h; al[ks][0] = (_Float16)(o0 - (float)h);
      h = (_Float16)o1; ah[ks][1] = h; al[ks][1] = (_Float16)(o1 - (float)h);
      h = (_Float16)o2; ah[ks][2] = h; al[ks][2] = (_Float16)(o2 - (float)h);
      h = (_Float16)o3; ah[ks][3] = h; al[ks][3] = (_Float16)(o3 - (float)h);
      h = (_Float16)o4; ah[ks][4] = h; al[ks][4] = (_Float16)(o4 - (float)h);
      h = (_Float16)o5; ah[ks][5] = h; al[ks][5] = (_Float16)(o5 - (float)h);
      h = (_Float16)o6; ah[ks][6] = h; al[ks][6] = (_Float16)(o6 - (float)h);
      h = (_Float16)o7; ah[ks][7] = h; al[ks][7] = (_Float16)(o7 - (float)h);
    }
  }

  WRITE(0);                           // slot0 <- hi-chunk0
  ISSUE(1);                           // hi-chunk1 in flight

  // row sum: butterfly over the 4 k-slices (lanes xor 16, 32); deterministic
  {
    float v1 = accq + __shfl_xor(accq, 16);
    float sxrow = v1 + __shfl_xor(v1, 32);
    if (lane < 16) sxs[wv * 16 + lane] = sxrow;
  }
  __syncthreads();                    // slot0 + sxs visible

  // ---- chunk loop: 20 x (16 codes); argmin folded per chunk ----
  float bv[4];
  int   bix[4];
  #pragma unroll
  for (int r = 0; r < 4; ++r) { bv[r] = 3.4e38f; bix[r] = 0x7fffffff; }

  float sxr[4];
  #pragma unroll
  for (int r = 0; r < 4; ++r) sxr[r] = sxs[wv * 16 + g * 4 + r];

  for (int c = 0; c < 20; ++c) {
    // WRITE hi-chunk c+1 (staged last iter), then ISSUE hi-chunk c+2
    if (c + 1 < 20) WRITE((c + 1) & 1);
    if (c + 2 < 20) ISSUE(c + 2);

    // COMPUTE chunk c: bh from LDS slot c&1, bl straight from L2 (issued
    // first so all 8 loads are in flight before first use)
    {
      const _Float16* bb = Bbuf[c & 1] + lane * 8;
      const _Float16* blp = cbx + (size_t)c * 8192 + 4096 + lane * 8; // lo half
      half8 blr[8];
      #pragma unroll
      for (int ks = 0; ks < 8; ++ks) blr[ks] = *(const half8*)(blp + ks * 512);

      f32x4 acc = (f32x4){0.f, 0.f, 0.f, 0.f};
      #pragma unroll
      for (int ks = 0; ks < 8; ++ks) {
        half8 bh = *(const half8*)(bb + ks * 512);
        acc = __builtin_amdgcn_mfma_f32_16x16x32_f16(ah[ks], bh, acc, 0, 0, 0);
        acc = __builtin_amdgcn_mfma_f32_16x16x32_f16(ah[ks], blr[ks], acc, 0, 0, 0);
        acc = __builtin_amdgcn_mfma_f32_16x16x32_f16(al[ks], bh, acc, 0, 0, 0);
      }
      // d2 = (sx - 2*dot) + cn  (exact rounding-matched expression)
      // C/D layout: col = lane&15 (code), row = (lane>>4)*4 + r
      const int code = c * 16 + c15;
      const float cn = cnorm[code];
      #pragma unroll
      for (int r = 0; r < 4; ++r) {
        const float d2 = (sxr[r] - 2.0f * acc[r]) + cn;
        if (d2 < bv[r] || (d2 == bv[r] && code < bix[r])) { bv[r] = d2; bix[r] = code; }
      }
    }
    if (c < 19) __syncthreads();      // slot (c+1)&1 ready for next iteration
  }

  // ---- butterfly argmin across the 16 lanes (columns) ----
  #pragma unroll
  for (int off = 8; off >= 1; off >>= 1) {
    #pragma unroll
    for (int r = 0; r < 4; ++r) {
      const float ov = __shfl_xor(bv[r], off);
      const int   oi = __shfl_xor(bix[r], off);
      if (ov < bv[r] || (ov == bv[r] && oi < bix[r])) { bv[r] = ov; bix[r] = oi; }
    }
  }
  if (c15 == 0) {
    #pragma unroll
    for (int r = 0; r < 4; ++r) {
      const int row = wv * 16 + g * 4 + r;     // local row 0..63
      bsel[row] = bix[r];
      out[(size_t)NROW * D + row0 + row] = (float)bix[r];
    }
  }
  __syncthreads();

  // ---- gather chosen codes (exact f32 copy), 4 threads per row ----
  {
    const int lr = t >> 2;            // 0..63
    const int q = t & 3;
    const int code = bsel[lr];
    const float* cp = cb + (size_t)code * D;
    float* op = out + (size_t)(row0 + lr) * D;
    #pragma unroll
    for (int e = 0; e < 16; ++e) {
      *(float4*)(op + e * 16 + q * 4) = *(const float4*)(cp + e * 16 + q * 4);
    }
  }
#undef ISSUE
#undef WRITE
}

extern "C" void kernel_launch(void* const* d_in, const int* in_sizes, int n_in,
                              void* d_out, int out_size, void* d_ws, size_t ws_size,
                              hipStream_t stream) {
  const float* x    = (const float*)d_in[0];
  const float* w    = (const float*)d_in[1];
  const float* bias = (const float*)d_in[2];
  const float* cb   = (const float*)d_in[3];
  float* out = (float*)d_out;

  unsigned long long* acc = (unsigned long long*)d_ws;
  float* meanb = (float*)((char*)d_ws + 4096);
  float* rsb   = meanb + 256;
  float* cnorm = rsb + 256;
  _Float16* cbx = (_Float16*)((char*)d_ws + 8192);   // 320 KB

  k_cbprep<<<161, 64, 0, stream>>>(cb, cbx, acc);    // prep + zero (merged)
  k_stats_partial<<<128, 256, 0, stream>>>(x, acc);
  k_stats_final<<<2, 256, 0, stream>>>(acc, cb, meanb, rsb, cnorm);
  k_main<<<NROW / 64, 256, 0, stream>>>(x, w, bias, cb, meanb, rsb, cnorm, cbx, out);
}

// Round 20
// 178.087 us; speedup vs baseline: 1.2880x; 1.2880x over previous
//
#include <hip/hip_runtime.h>
#include <hip/hip_bf16.h>

#define NROW 131072   // B*L
#define D 256
#define K 320
#define BN_EPS 1e-5f
#define FIXSCALE 16777216.0f   // 2^24 fixed-point for deterministic atomics

typedef _Float16 half8 __attribute__((ext_vector_type(8)));
typedef float f32x4 __attribute__((ext_vector_type(4)));

// ws layout:
//   u64 acc[512]   @ 0      (4 KB)
//   f32 meanb[256] @ 4096
//   f32 rsb[256]   @ 5120
//   f32 cnorm[320] @ 6144
//   f16 cbx        @ 8192   (320 KB) codebook fragments:
//     tile nt(0..19) = 16 codes, hl(0=hi,1=lo), ks(0..7):
//     halfs at ((nt*2+hl)*8+ks)*512 + lane*8  -> tile nt = 16 KB at nt*16384 B

// ---------------- kernel 1: per-block channel partials -> fixed-point atomics
// float4 loads; ascending-row accumulation -> partials bit-identical to the
// scalar version (verified passing R17/R18/R19).
__global__ __launch_bounds__(256) void k_stats_partial(const float* __restrict__ x,
                                                       unsigned long long* __restrict__ acc) {
  const int q = threadIdx.x & 63;     // channel quad 0..63
  const int g2 = threadIdx.x >> 6;    // slab within block
  const int slab = (int)blockIdx.x * 4 + g2;   // 0..511
  const float* p = x + (size_t)slab * 256 * D + q * 4;
  float s0 = 0.f, s1 = 0.f, s2 = 0.f, s3 = 0.f;
  float q0 = 0.f, q1 = 0.f, q2 = 0.f, q3 = 0.f;
  #pragma unroll 4
  for (int r = 0; r < 256; ++r) {
    float4 v = *(const float4*)(p + (size_t)r * D);
    s0 += v.x; q0 = fmaf(v.x, v.x, q0);
    s1 += v.y; q1 = fmaf(v.y, v.y, q1);
    s2 += v.z; q2 = fmaf(v.z, v.z, q2);
    s3 += v.w; q3 = fmaf(v.w, v.w, q3);
  }
  atomicAdd(&acc[q * 4 + 0],       (unsigned long long)(long long)llrintf(s0 * FIXSCALE));
  atomicAdd(&acc[q * 4 + 1],       (unsigned long long)(long long)llrintf(s1 * FIXSCALE));
  atomicAdd(&acc[q * 4 + 2],       (unsigned long long)(long long)llrintf(s2 * FIXSCALE));
  atomicAdd(&acc[q * 4 + 3],       (unsigned long long)(long long)llrintf(s3 * FIXSCALE));
  atomicAdd(&acc[256 + q * 4 + 0], (unsigned long long)(long long)llrintf(q0 * FIXSCALE));
  atomicAdd(&acc[256 + q * 4 + 1], (unsigned long long)(long long)llrintf(q1 * FIXSCALE));
  atomicAdd(&acc[256 + q * 4 + 2], (unsigned long long)(long long)llrintf(q2 * FIXSCALE));
  atomicAdd(&acc[256 + q * 4 + 3], (unsigned long long)(long long)llrintf(q3 * FIXSCALE));
}

// ---------------- kernel 2: finalize stats + codebook norms -----------------
__global__ __launch_bounds__(256) void k_stats_final(const unsigned long long* __restrict__ acc,
                                                     const float* __restrict__ cb,
                                                     float* __restrict__ meanb,
                                                     float* __restrict__ rsb,
                                                     float* __restrict__ cnorm) {
  const int t = threadIdx.x;
  if (blockIdx.x == 0) {
    double s = (double)(long long)acc[t]       / (double)FIXSCALE;
    double q = (double)(long long)acc[256 + t] / (double)FIXSCALE;
    double mean = s / (double)NROW;
    double var  = q / (double)NROW - mean * mean;
    meanb[t] = (float)mean;
    rsb[t]   = (float)(1.0 / sqrt(var + (double)BN_EPS));
  } else {
    for (int code = t; code < K; code += 256) {
      const float* c = cb + (size_t)code * D;
      float s = 0.f;
      for (int dd = 0; dd < D; ++dd) s = fmaf(c[dd], c[dd], s);
      cnorm[code] = s;
    }
  }
}

// ---------------- kernel 2b: split codebook to fp16 hi/lo fragments ---------
// blocks 0..159: prep (nt = b>>3, ks = b&7); block 160: zero stat accumulators
__global__ __launch_bounds__(64) void k_cbprep(const float* __restrict__ cb,
                                               _Float16* __restrict__ cbx,
                                               unsigned long long* __restrict__ acc) {
  const int b = blockIdx.x;
  const int l = threadIdx.x;
  if (b == 160) {
    #pragma unroll
    for (int j = 0; j < 8; ++j) acc[j * 64 + l] = 0ull;
    return;
  }
  const int nt = b >> 3;
  const int ks = b & 7;
  const int code = nt * 16 + (l & 15);
  const int d0 = ks * 32 + (l >> 4) * 8;
  const float* src = cb + (size_t)code * D + d0;
  const size_t bh = ((size_t)(nt * 2 + 0) * 8 + ks) * 512 + l * 8;
  const size_t bl = ((size_t)(nt * 2 + 1) * 8 + ks) * 512 + l * 8;
  #pragma unroll
  for (int j = 0; j < 8; ++j) {
    float v = src[j];
    _Float16 h = (_Float16)v;
    _Float16 lo = (_Float16)(v - (float)h);
    cbx[bh + j] = h;
    cbx[bl + j] = lo;
  }
}

// ---------------- kernel 3: R14 verbatim — the measured structural optimum --
// 2048 blocks x 256 thr (4 waves x 16 rows). Wave wv owns rows row0+wv*16..+16
// vs ALL 320 codes. Chunk = 16 codes (16 KB), 2 LDS slots (33 KB -> 4
// blocks/CU = 16 waves/CU); reg-staged depth-2 pipeline. Measured 109 µs,
// MfmaUtil 24%, zero bank conflicts; every structural variant (rows/wave=32,
// global_load_lds, 8-wave blocks, 4-slot, split-B via L2) regressed.
__global__ __launch_bounds__(256) void k_main(const float* __restrict__ x,
                                              const float* __restrict__ w,
                                              const float* __restrict__ bias,
                                              const float* __restrict__ cb,
                                              const float* __restrict__ meanb,
                                              const float* __restrict__ rsb,
                                              const float* __restrict__ cnorm,
                                              const _Float16* __restrict__ cbx,
                                              float* __restrict__ out) {
  __shared__ _Float16 Bbuf[2][8192];    // 2 x 16 KB chunk slots
  __shared__ float sxs[64];             // per-row |xb|^2
  __shared__ int bsel[64];

  const int t = threadIdx.x;
  const int lane = t & 63;
  const int wv = t >> 6;              // wave 0..3
  const int c15 = lane & 15;
  const int g = lane >> 4;
  const int row0 = (int)blockIdx.x * 64;

  // ---- staging: chunk c = 16 KB; 256 thr x 64 B = 4 x float4 per thread ----
  float4 s0, s1, s2, s3;
  const char* stg_src = (const char*)cbx + (size_t)t * 16;
#define ISSUE(c) {                                                  \
    const char* p_ = stg_src + (size_t)(c) * 16384;                 \
    s0 = *(const float4*)(p_);                                      \
    s1 = *(const float4*)(p_ + 4096);                               \
    s2 = *(const float4*)(p_ + 8192);                               \
    s3 = *(const float4*)(p_ + 12288);                              \
  }
#define WRITE(b) {                                                  \
    char* q_ = (char*)Bbuf[(b)] + t * 16;                           \
    *(float4*)(q_)         = s0;                                    \
    *(float4*)(q_ + 4096)  = s1;                                    \
    *(float4*)(q_ + 8192)  = s2;                                    \
    *(float4*)(q_ + 12288) = s3;                                    \
  }

  ISSUE(0);

  // ---- x -> A fragments in registers (normalize + fp16 hi/lo split) ----
  // lane l: row = row0 + wv*16 + (l&15), k-elems (l>>4)*8 + ks*32 .. +8
  half8 ah[8], al[8];
  float accq = 0.f;
  {
    const int arow = row0 + wv * 16 + c15;
    const int dbase = g * 8;
    const float* xp = x + (size_t)arow * D + dbase;
    #pragma unroll
    for (int ks = 0; ks < 8; ++ks) {
      const int d0 = dbase + ks * 32;
      float4 xa = *(const float4*)(xp + ks * 32);
      float4 xb2 = *(const float4*)(xp + ks * 32 + 4);
      float4 m0 = *(const float4*)(meanb + d0);
      float4 m1 = *(const float4*)(meanb + d0 + 4);
      float4 r0 = *(const float4*)(rsb + d0);
      float4 r1 = *(const float4*)(rsb + d0 + 4);
      float4 w0 = *(const float4*)(w + d0);
      float4 w1 = *(const float4*)(w + d0 + 4);
      float4 b0 = *(const float4*)(bias + d0);
      float4 b1 = *(const float4*)(bias + d0 + 4);
      float o0 = ((xa.x - m0.x) * r0.x) * w0.x + b0.x;
      float o1 = ((xa.y - m0.y) * r0.y) * w0.y + b0.y;
      float o2 = ((xa.z - m0.z) * r0.z) * w0.z + b0.z;
      float o3 = ((xa.w - m0.w) * r0.w) * w0.w + b0.w;
      float o4 = ((xb2.x - m1.x) * r1.x) * w1.x + b1.x;
      float o5 = ((xb2.y - m1.y) * r1.y) * w1.y + b1.y;
      float o6 = ((xb2.z - m1.z) * r1.z) * w1.z + b1.z;
      float o7 = ((xb2.w - m1.w) * r1.w) * w1.w + b1.w;
      accq = fmaf(o0, o0, accq); accq = fmaf(o1, o1, accq);
      accq = fmaf(o2, o2, accq); accq = fmaf(o3, o3, accq);
      accq = fmaf(o4, o4, accq); accq = fmaf(o5, o5, accq);
      accq = fmaf(o6, o6, accq); accq = fmaf(o7, o7, accq);
      _Float16 h;
      h = (_Float16)o0; ah[ks][0] = h; al[ks][0] = (_Float16)(o0 - (float)h);
      h = (_Float16)o1; ah[ks][1] = h; al[ks][1] = (_Float16)(o1 - (float)h);
      h = (_Float16)o2; ah[ks][2] = h; al[ks][2] = (_Float16)(o2 - (float)h);
      h = (_Float16)o3; ah[ks][3] = h; al[ks][3] = (_Float16)(o3 - (float)h);
      h = (_Float16)o4; ah[ks][4] = h; al[ks][4] = (_Float16)(o4 - (float)h);
      h = (_Float16)o5; ah[ks][5] = h; al[ks][5] = (_Float16)(o5 - (float)h);
      h = (_Float16)o6; ah[ks][6] = h; al[ks][6] = (_Float16)(o6 - (float)h);
      h = (_Float16)o7; ah[ks][7] = h; al[ks][7] = (_Float16)(o7 - (float)h);
    }
  }

  WRITE(0);                           // slot0 <- chunk0
  ISSUE(1);                           // chunk1 in flight

  // row sum: butterfly over the 4 k-slices (lanes xor 16, 32); deterministic
  {
    float v1 = accq + __shfl_xor(accq, 16);
    float sxrow = v1 + __shfl_xor(v1, 32);
    if (lane < 16) sxs[wv * 16 + lane] = sxrow;
  }
  __syncthreads();                    // slot0 + sxs visible

  // ---- chunk loop: 20 x (16 codes); argmin folded per chunk ----
  float bv[4];
  int   bix[4];
  #pragma unroll
  for (int r = 0; r < 4; ++r) { bv[r] = 3.4e38f; bix[r] = 0x7fffffff; }

  float sxr[4];
  #pragma unroll
  for (int r = 0; r < 4; ++r) sxr[r] = sxs[wv * 16 + g * 4 + r];

  for (int c = 0; c < 20; ++c) {
    // WRITE chunk c+1 (staged in regs last iter; that slot's readers finished
    // before the previous barrier), then ISSUE chunk c+2 (flies under COMPUTE)
    if (c + 1 < 20) WRITE((c + 1) & 1);
    if (c + 2 < 20) ISSUE(c + 2);

    // COMPUTE chunk c from slot c&1
    {
      const _Float16* bb = Bbuf[c & 1] + lane * 8;
      f32x4 acc = (f32x4){0.f, 0.f, 0.f, 0.f};
      #pragma unroll
      for (int ks = 0; ks < 8; ++ks) {
        half8 bh = *(const half8*)(bb + ks * 512);          // hl=0
        half8 bl = *(const half8*)(bb + 4096 + ks * 512);   // hl=1
        acc = __builtin_amdgcn_mfma_f32_16x16x32_f16(ah[ks], bh, acc, 0, 0, 0);
        acc = __builtin_amdgcn_mfma_f32_16x16x32_f16(ah[ks], bl, acc, 0, 0, 0);
        acc = __builtin_amdgcn_mfma_f32_16x16x32_f16(al[ks], bh, acc, 0, 0, 0);
      }
      // d2 = (sx - 2*dot) + cn  (exact rounding-matched expression)
      // C/D layout: col = lane&15 (code), row = (lane>>4)*4 + r
      const int code = c * 16 + c15;
      const float cn = cnorm[code];
      #pragma unroll
      for (int r = 0; r < 4; ++r) {
        const float d2 = (sxr[r] - 2.0f * acc[r]) + cn;
        if (d2 < bv[r] || (d2 == bv[r] && code < bix[r])) { bv[r] = d2; bix[r] = code; }
      }
    }
    if (c < 19) __syncthreads();      // slot (c+1)&1 ready for next iteration
  }

  // ---- butterfly argmin across the 16 lanes (columns) ----
  #pragma unroll
  for (int off = 8; off >= 1; off >>= 1) {
    #pragma unroll
    for (int r = 0; r < 4; ++r) {
      const float ov = __shfl_xor(bv[r], off);
      const int   oi = __shfl_xor(bix[r], off);
      if (ov < bv[r] || (ov == bv[r] && oi < bix[r])) { bv[r] = ov; bix[r] = oi; }
    }
  }
  if (c15 == 0) {
    #pragma unroll
    for (int r = 0; r < 4; ++r) {
      const int row = wv * 16 + g * 4 + r;     // local row 0..63
      bsel[row] = bix[r];
      out[(size_t)NROW * D + row0 + row] = (float)bix[r];
    }
  }
  __syncthreads();

  // ---- gather chosen codes (exact f32 copy), 4 threads per row ----
  {
    const int lr = t >> 2;            // 0..63
    const int q = t & 3;
    const int code = bsel[lr];
    const float* cp = cb + (size_t)code * D;
    float* op = out + (size_t)(row0 + lr) * D;
    #pragma unroll
    for (int e = 0; e < 16; ++e) {
      *(float4*)(op + e * 16 + q * 4) = *(const float4*)(cp + e * 16 + q * 4);
    }
  }
#undef ISSUE
#undef WRITE
}

extern "C" void kernel_launch(void* const* d_in, const int* in_sizes, int n_in,
                              void* d_out, int out_size, void* d_ws, size_t ws_size,
                              hipStream_t stream) {
  const float* x    = (const float*)d_in[0];
  const float* w    = (const float*)d_in[1];
  const float* bias = (const float*)d_in[2];
  const float* cb   = (const float*)d_in[3];
  float* out = (float*)d_out;

  unsigned long long* acc = (unsigned long long*)d_ws;
  float* meanb = (float*)((char*)d_ws + 4096);
  float* rsb   = meanb + 256;
  float* cnorm = rsb + 256;
  _Float16* cbx = (_Float16*)((char*)d_ws + 8192);   // 320 KB

  k_cbprep<<<161, 64, 0, stream>>>(cb, cbx, acc);    // prep + zero (merged)
  k_stats_partial<<<128, 256, 0, stream>>>(x, acc);
  k_stats_final<<<2, 256, 0, stream>>>(acc, cb, meanb, rsb, cnorm);
  k_main<<<NROW / 64, 256, 0, stream>>>(x, w, bias, cb, meanb, rsb, cnorm, cbx, out);
}

// Round 21
// 174.184 us; speedup vs baseline: 1.3168x; 1.0224x over previous
//
#include <hip/hip_runtime.h>
#include <hip/hip_bf16.h>

#define NROW 131072   // B*L
#define D 256
#define K 320
#define BN_EPS 1e-5f
#define FIXSCALE 16777216.0f   // 2^24 fixed-point for deterministic atomics

typedef _Float16 half8 __attribute__((ext_vector_type(8)));
typedef float f32x4 __attribute__((ext_vector_type(4)));

// ws layout:
//   u64 acc[512]   @ 0      (4 KB)
//   f32 meanb[256] @ 4096
//   f32 rsb[256]   @ 5120
//   f32 cnorm[320] @ 6144
//   f16 cbx        @ 8192   (320 KB) codebook fragments:
//     tile nt(0..19) = 16 codes, hl(0=hi,1=lo), ks(0..7):
//     halfs at ((nt*2+hl)*8+ks)*512 + lane*8  -> tile nt = 16 KB at nt*16384 B

// ---------------- kernel 0: zero the fixed-point accumulators ---------------
__global__ __launch_bounds__(256) void k_zero(unsigned long long* __restrict__ acc) {
  acc[threadIdx.x] = 0ull;
  acc[256 + threadIdx.x] = 0ull;
}

// ---------------- kernel 1: merged cbprep + stats partials ------------------
// blocks 0..159: codebook fp16 hi/lo fragment prep (nt = b>>3, ks = b&7).
// blocks 160..671: stats for slab b-160 (256 rows): thread q sums channels
// 4q..4q+3 over rows IN ASCENDING ORDER (float4 loads) -> per-(slab,channel)
// f32 partials bit-identical to all passing rounds; fixed-point atomics are
// order-independent. 512 slab-blocks -> all 256 CUs busy; cbprep rides along.
__global__ __launch_bounds__(64) void k_prep_stats(const float* __restrict__ x,
                                                   const float* __restrict__ cb,
                                                   _Float16* __restrict__ cbx,
                                                   unsigned long long* __restrict__ acc) {
  const int b = blockIdx.x;
  const int l = threadIdx.x;
  if (b < 160) {
    const int nt = b >> 3;
    const int ks = b & 7;
    const int code = nt * 16 + (l & 15);
    const int d0 = ks * 32 + (l >> 4) * 8;
    const float* src = cb + (size_t)code * D + d0;
    const size_t bh = ((size_t)(nt * 2 + 0) * 8 + ks) * 512 + l * 8;
    const size_t bl = ((size_t)(nt * 2 + 1) * 8 + ks) * 512 + l * 8;
    #pragma unroll
    for (int j = 0; j < 8; ++j) {
      float v = src[j];
      _Float16 h = (_Float16)v;
      _Float16 lo = (_Float16)(v - (float)h);
      cbx[bh + j] = h;
      cbx[bl + j] = lo;
    }
    return;
  }
  const int slab = b - 160;           // 0..511
  const float* p = x + (size_t)slab * 256 * D + l * 4;
  float s0 = 0.f, s1 = 0.f, s2 = 0.f, s3 = 0.f;
  float q0 = 0.f, q1 = 0.f, q2 = 0.f, q3 = 0.f;
  #pragma unroll 8
  for (int r = 0; r < 256; ++r) {
    float4 v = *(const float4*)(p + (size_t)r * D);
    s0 += v.x; q0 = fmaf(v.x, v.x, q0);
    s1 += v.y; q1 = fmaf(v.y, v.y, q1);
    s2 += v.z; q2 = fmaf(v.z, v.z, q2);
    s3 += v.w; q3 = fmaf(v.w, v.w, q3);
  }
  atomicAdd(&acc[l * 4 + 0],       (unsigned long long)(long long)llrintf(s0 * FIXSCALE));
  atomicAdd(&acc[l * 4 + 1],       (unsigned long long)(long long)llrintf(s1 * FIXSCALE));
  atomicAdd(&acc[l * 4 + 2],       (unsigned long long)(long long)llrintf(s2 * FIXSCALE));
  atomicAdd(&acc[l * 4 + 3],       (unsigned long long)(long long)llrintf(s3 * FIXSCALE));
  atomicAdd(&acc[256 + l * 4 + 0], (unsigned long long)(long long)llrintf(q0 * FIXSCALE));
  atomicAdd(&acc[256 + l * 4 + 1], (unsigned long long)(long long)llrintf(q1 * FIXSCALE));
  atomicAdd(&acc[256 + l * 4 + 2], (unsigned long long)(long long)llrintf(q2 * FIXSCALE));
  atomicAdd(&acc[256 + l * 4 + 3], (unsigned long long)(long long)llrintf(q3 * FIXSCALE));
}

// ---------------- kernel 2: finalize stats + codebook norms -----------------
__global__ __launch_bounds__(256) void k_stats_final(const unsigned long long* __restrict__ acc,
                                                     const float* __restrict__ cb,
                                                     float* __restrict__ meanb,
                                                     float* __restrict__ rsb,
                                                     float* __restrict__ cnorm) {
  const int t = threadIdx.x;
  if (blockIdx.x == 0) {
    double s = (double)(long long)acc[t]       / (double)FIXSCALE;
    double q = (double)(long long)acc[256 + t] / (double)FIXSCALE;
    double mean = s / (double)NROW;
    double var  = q / (double)NROW - mean * mean;
    meanb[t] = (float)mean;
    rsb[t]   = (float)(1.0 / sqrt(var + (double)BN_EPS));
  } else {
    for (int code = t; code < K; code += 256) {
      const float* c = cb + (size_t)code * D;
      float s = 0.f;
      for (int dd = 0; dd < D; ++dd) s = fmaf(c[dd], c[dd], s);
      cnorm[code] = s;
    }
  }
}

// ---------------- kernel 3: R14 verbatim — the measured structural optimum --
// 2048 blocks x 256 thr (4 waves x 16 rows). Wave wv owns rows row0+wv*16..+16
// vs ALL 320 codes. Chunk = 16 codes (16 KB), 2 LDS slots (33 KB -> 4
// blocks/CU = 16 waves/CU); reg-staged depth-2 pipeline. Measured 108.6 µs,
// MfmaUtil 24%, zero bank conflicts; every structural variant (rows/wave=32,
// global_load_lds, 8-wave blocks, 4-slot, split-B via L2) regressed.
__global__ __launch_bounds__(256) void k_main(const float* __restrict__ x,
                                              const float* __restrict__ w,
                                              const float* __restrict__ bias,
                                              const float* __restrict__ cb,
                                              const float* __restrict__ meanb,
                                              const float* __restrict__ rsb,
                                              const float* __restrict__ cnorm,
                                              const _Float16* __restrict__ cbx,
                                              float* __restrict__ out) {
  __shared__ _Float16 Bbuf[2][8192];    // 2 x 16 KB chunk slots
  __shared__ float sxs[64];             // per-row |xb|^2
  __shared__ int bsel[64];

  const int t = threadIdx.x;
  const int lane = t & 63;
  const int wv = t >> 6;              // wave 0..3
  const int c15 = lane & 15;
  const int g = lane >> 4;
  const int row0 = (int)blockIdx.x * 64;

  // ---- staging: chunk c = 16 KB; 256 thr x 64 B = 4 x float4 per thread ----
  float4 s0, s1, s2, s3;
  const char* stg_src = (const char*)cbx + (size_t)t * 16;
#define ISSUE(c) {                                                  \
    const char* p_ = stg_src + (size_t)(c) * 16384;                 \
    s0 = *(const float4*)(p_);                                      \
    s1 = *(const float4*)(p_ + 4096);                               \
    s2 = *(const float4*)(p_ + 8192);                               \
    s3 = *(const float4*)(p_ + 12288);                              \
  }
#define WRITE(b) {                                                  \
    char* q_ = (char*)Bbuf[(b)] + t * 16;                           \
    *(float4*)(q_)         = s0;                                    \
    *(float4*)(q_ + 4096)  = s1;                                    \
    *(float4*)(q_ + 8192)  = s2;                                    \
    *(float4*)(q_ + 12288) = s3;                                    \
  }

  ISSUE(0);

  // ---- x -> A fragments in registers (normalize + fp16 hi/lo split) ----
  // lane l: row = row0 + wv*16 + (l&15), k-elems (l>>4)*8 + ks*32 .. +8
  half8 ah[8], al[8];
  float accq = 0.f;
  {
    const int arow = row0 + wv * 16 + c15;
    const int dbase = g * 8;
    const float* xp = x + (size_t)arow * D + dbase;
    #pragma unroll
    for (int ks = 0; ks < 8; ++ks) {
      const int d0 = dbase + ks * 32;
      float4 xa = *(const float4*)(xp + ks * 32);
      float4 xb2 = *(const float4*)(xp + ks * 32 + 4);
      float4 m0 = *(const float4*)(meanb + d0);
      float4 m1 = *(const float4*)(meanb + d0 + 4);
      float4 r0 = *(const float4*)(rsb + d0);
      float4 r1 = *(const float4*)(rsb + d0 + 4);
      float4 w0 = *(const float4*)(w + d0);
      float4 w1 = *(const float4*)(w + d0 + 4);
      float4 b0 = *(const float4*)(bias + d0);
      float4 b1 = *(const float4*)(bias + d0 + 4);
      float o0 = ((xa.x - m0.x) * r0.x) * w0.x + b0.x;
      float o1 = ((xa.y - m0.y) * r0.y) * w0.y + b0.y;
      float o2 = ((xa.z - m0.z) * r0.z) * w0.z + b0.z;
      float o3 = ((xa.w - m0.w) * r0.w) * w0.w + b0.w;
      float o4 = ((xb2.x - m1.x) * r1.x) * w1.x + b1.x;
      float o5 = ((xb2.y - m1.y) * r1.y) * w1.y + b1.y;
      float o6 = ((xb2.z - m1.z) * r1.z) * w1.z + b1.z;
      float o7 = ((xb2.w - m1.w) * r1.w) * w1.w + b1.w;
      accq = fmaf(o0, o0, accq); accq = fmaf(o1, o1, accq);
      accq = fmaf(o2, o2, accq); accq = fmaf(o3, o3, accq);
      accq = fmaf(o4, o4, accq); accq = fmaf(o5, o5, accq);
      accq = fmaf(o6, o6, accq); accq = fmaf(o7, o7, accq);
      _Float16 h;
      h = (_Float16)o0; ah[ks][0] = h; al[ks][0] = (_Float16)(o0 - (float)h);
      h = (_Float16)o1; ah[ks][1] = h; al[ks][1] = (_Float16)(o1 - (float)h);
      h = (_Float16)o2; ah[ks][2] = h; al[ks][2] = (_Float16)(o2 - (float)h);
      h = (_Float16)o3; ah[ks][3] = h; al[ks][3] = (_Float16)(o3 - (float)h);
      h = (_Float16)o4; ah[ks][4] = h; al[ks][4] = (_Float16)(o4 - (float)h);
      h = (_Float16)o5; ah[ks][5] = h; al[ks][5] = (_Float16)(o5 - (float)h);
      h = (_Float16)o6; ah[ks][6] = h; al[ks][6] = (_Float16)(o6 - (float)h);
      h = (_Float16)o7; ah[ks][7] = h; al[ks][7] = (_Float16)(o7 - (float)h);
    }
  }

  WRITE(0);                           // slot0 <- chunk0
  ISSUE(1);                           // chunk1 in flight

  // row sum: butterfly over the 4 k-slices (lanes xor 16, 32); deterministic
  {
    float v1 = accq + __shfl_xor(accq, 16);
    float sxrow = v1 + __shfl_xor(v1, 32);
    if (lane < 16) sxs[wv * 16 + lane] = sxrow;
  }
  __syncthreads();                    // slot0 + sxs visible

  // ---- chunk loop: 20 x (16 codes); argmin folded per chunk ----
  float bv[4];
  int   bix[4];
  #pragma unroll
  for (int r = 0; r < 4; ++r) { bv[r] = 3.4e38f; bix[r] = 0x7fffffff; }

  float sxr[4];
  #pragma unroll
  for (int r = 0; r < 4; ++r) sxr[r] = sxs[wv * 16 + g * 4 + r];

  for (int c = 0; c < 20; ++c) {
    // WRITE chunk c+1 (staged in regs last iter; that slot's readers finished
    // before the previous barrier), then ISSUE chunk c+2 (flies under COMPUTE)
    if (c + 1 < 20) WRITE((c + 1) & 1);
    if (c + 2 < 20) ISSUE(c + 2);

    // COMPUTE chunk c from slot c&1
    {
      const _Float16* bb = Bbuf[c & 1] + lane * 8;
      f32x4 acc = (f32x4){0.f, 0.f, 0.f, 0.f};
      #pragma unroll
      for (int ks = 0; ks < 8; ++ks) {
        half8 bh = *(const half8*)(bb + ks * 512);          // hl=0
        half8 bl = *(const half8*)(bb + 4096 + ks * 512);   // hl=1
        acc = __builtin_amdgcn_mfma_f32_16x16x32_f16(ah[ks], bh, acc, 0, 0, 0);
        acc = __builtin_amdgcn_mfma_f32_16x16x32_f16(ah[ks], bl, acc, 0, 0, 0);
        acc = __builtin_amdgcn_mfma_f32_16x16x32_f16(al[ks], bh, acc, 0, 0, 0);
      }
      // d2 = (sx - 2*dot) + cn  (exact rounding-matched expression)
      // C/D layout: col = lane&15 (code), row = (lane>>4)*4 + r
      const int code = c * 16 + c15;
      const float cn = cnorm[code];
      #pragma unroll
      for (int r = 0; r < 4; ++r) {
        const float d2 = (sxr[r] - 2.0f * acc[r]) + cn;
        if (d2 < bv[r] || (d2 == bv[r] && code < bix[r])) { bv[r] = d2; bix[r] = code; }
      }
    }
    if (c < 19) __syncthreads();      // slot (c+1)&1 ready for next iteration
  }

  // ---- butterfly argmin across the 16 lanes (columns) ----
  #pragma unroll
  for (int off = 8; off >= 1; off >>= 1) {
    #pragma unroll
    for (int r = 0; r < 4; ++r) {
      const float ov = __shfl_xor(bv[r], off);
      const int   oi = __shfl_xor(bix[r], off);
      if (ov < bv[r] || (ov == bv[r] && oi < bix[r])) { bv[r] = ov; bix[r] = oi; }
    }
  }
  if (c15 == 0) {
    #pragma unroll
    for (int r = 0; r < 4; ++r) {
      const int row = wv * 16 + g * 4 + r;     // local row 0..63
      bsel[row] = bix[r];
      out[(size_t)NROW * D + row0 + row] = (float)bix[r];
    }
  }
  __syncthreads();

  // ---- gather chosen codes (exact f32 copy), 4 threads per row ----
  {
    const int lr = t >> 2;            // 0..63
    const int q = t & 3;
    const int code = bsel[lr];
    const float* cp = cb + (size_t)code * D;
    float* op = out + (size_t)(row0 + lr) * D;
    #pragma unroll
    for (int e = 0; e < 16; ++e) {
      *(float4*)(op + e * 16 + q * 4) = *(const float4*)(cp + e * 16 + q * 4);
    }
  }
#undef ISSUE
#undef WRITE
}

extern "C" void kernel_launch(void* const* d_in, const int* in_sizes, int n_in,
                              void* d_out, int out_size, void* d_ws, size_t ws_size,
                              hipStream_t stream) {
  const float* x    = (const float*)d_in[0];
  const float* w    = (const float*)d_in[1];
  const float* bias = (const float*)d_in[2];
  const float* cb   = (const float*)d_in[3];
  float* out = (float*)d_out;

  unsigned long long* acc = (unsigned long long*)d_ws;
  float* meanb = (float*)((char*)d_ws + 4096);
  float* rsb   = meanb + 256;
  float* cnorm = rsb + 256;
  _Float16* cbx = (_Float16*)((char*)d_ws + 8192);   // 320 KB

  k_zero<<<1, 256, 0, stream>>>(acc);
  k_prep_stats<<<672, 64, 0, stream>>>(x, cb, cbx, acc);  // cbprep || stats
  k_stats_final<<<2, 256, 0, stream>>>(acc, cb, meanb, rsb, cnorm);
  k_main<<<NROW / 64, 256, 0, stream>>>(x, w, bias, cb, meanb, rsb, cnorm, cbx, out);
}